// Round 29
// baseline (36.994 us; speedup 1.0000x reference)
//
#include <hip/hip_runtime.h>

#define B_  4
#define NQ_ 256
#define NK_ 512
#define H_  256
#define PADK 520   // half8s per E row: stride 8320B, breaks 8KB aliasing

typedef _Float16 half8  __attribute__((ext_vector_type(8)));
typedef _Float16 half4_t __attribute__((ext_vector_type(4)));

// 2*log2(e): exp2(x*TWO_LOG2E) = e^{2x}
#define TWO_LOG2E 2.8853900817779268f

// SPLIT-K4 gemm: 192 tiles (64x64, same global traffic as r25 -- r27 showed
// smaller tiles regress), 1024 threads; group g = tid>>8 owns K-quarter
// [g*64,+64) -> 4 waves/SIMD (2x r25's split-K2, which measured -2.1us).
// Partial-sum buffers ALIAS the stage LDS via union (dead after last read).
__global__ __launch_bounds__(1024)
void gemm_fused(const float* __restrict__ xq, const float* __restrict__ xk,
                const float* __restrict__ w1, const float* __restrict__ w2,
                _Float16* __restrict__ Ebuf,  // [B][32][PADK][8] halves
                float* __restrict__ Fbuf)     // [B][NQ][H]
{
    constexpr int BK = 32;
    const float* A; const float* Bm;
    int m0, n0, bz; bool iskt;
    {
        int id = blockIdx.x;
        if (id < 128) {                      // kt: M=H(o), N=NK(k)
            iskt = true;
            bz = id >> 5; int t = id & 31;
            m0 = (t >> 3) * 64; n0 = (t & 7) * 64;
            A = w1; Bm = xk + (long)bz * NK_ * H_;
        } else {                             // qt: M=NQ(q), N=H(o)
            iskt = false;
            id -= 128;
            bz = id >> 4; int t = id & 15;
            m0 = (t >> 2) * 64; n0 = (t & 3) * 64;
            A = xq + (long)bz * NQ_ * H_; Bm = w2;
        }
    }
    const int lda = H_, ldb = H_;
    const int ks = (blockIdx.x & 7) * BK;    // per-block K stagger (r22 win)

    __shared__ union {
        struct { float As[4][BK][68]; float Bs[4][BK][68]; } st;  // 69.6 KB
        float Cred[3][16][260];                                   // 49.9 KB
    } sm;

    const int tid  = threadIdx.x & 255;
    const int grp  = threadIdx.x >> 8;       // K-quarter owner (0..3)
    const int kofs = grp * 64;
    const int lrow = tid >> 2;
    const int lk   = (tid & 3) * 8;
    const int tm   = (tid >> 4) * 4;
    const int tn   = (tid & 15) * 4;

    float acc[4][4] = {};

    int kt0 = (ks + kofs) & (H_ - 1);
    float4 a0_r = *(const float4*)&A [(long)(m0 + lrow) * lda + kt0 + lk];
    float4 a1_r = *(const float4*)&A [(long)(m0 + lrow) * lda + kt0 + lk + 4];
    float4 b0_r = *(const float4*)&Bm[(long)(n0 + lrow) * ldb + kt0 + lk];
    float4 b1_r = *(const float4*)&Bm[(long)(n0 + lrow) * ldb + kt0 + lk + 4];
    float4 a0_n = a0_r, a1_n = a1_r, b0_n = b0_r, b1_n = b1_r;

    for (int t = 0; t < 64; t += BK) {       // 2 iters per group
        __syncthreads();
        sm.st.As[grp][lk+0][lrow]=a0_r.x; sm.st.As[grp][lk+1][lrow]=a0_r.y;
        sm.st.As[grp][lk+2][lrow]=a0_r.z; sm.st.As[grp][lk+3][lrow]=a0_r.w;
        sm.st.As[grp][lk+4][lrow]=a1_r.x; sm.st.As[grp][lk+5][lrow]=a1_r.y;
        sm.st.As[grp][lk+6][lrow]=a1_r.z; sm.st.As[grp][lk+7][lrow]=a1_r.w;
        sm.st.Bs[grp][lk+0][lrow]=b0_r.x; sm.st.Bs[grp][lk+1][lrow]=b0_r.y;
        sm.st.Bs[grp][lk+2][lrow]=b0_r.z; sm.st.Bs[grp][lk+3][lrow]=b0_r.w;
        sm.st.Bs[grp][lk+4][lrow]=b1_r.x; sm.st.Bs[grp][lk+5][lrow]=b1_r.y;
        sm.st.Bs[grp][lk+6][lrow]=b1_r.z; sm.st.Bs[grp][lk+7][lrow]=b1_r.w;
        if (t + BK < 64) {
            const int ktn = (ks + kofs + t + BK) & (H_ - 1);
            a0_n = *(const float4*)&A [(long)(m0 + lrow) * lda + ktn + lk];
            a1_n = *(const float4*)&A [(long)(m0 + lrow) * lda + ktn + lk + 4];
            b0_n = *(const float4*)&Bm[(long)(n0 + lrow) * ldb + ktn + lk];
            b1_n = *(const float4*)&Bm[(long)(n0 + lrow) * ldb + ktn + lk + 4];
        }
        __syncthreads();
        #pragma unroll
        for (int kk = 0; kk < BK; ++kk) {
            float4 av = *(const float4*)&sm.st.As[grp][kk][tm];
            float4 bv = *(const float4*)&sm.st.Bs[grp][kk][tn];
            float am[4] = {av.x, av.y, av.z, av.w};
            float bn[4] = {bv.x, bv.y, bv.z, bv.w};
            #pragma unroll
            for (int i = 0; i < 4; ++i)
                #pragma unroll
                for (int j = 0; j < 4; ++j)
                    acc[i][j] = fmaf(am[i], bn[j], acc[i][j]);
        }
        a0_r = a0_n; a1_r = a1_n; b0_r = b0_n; b1_r = b1_n;
    }

    // combine K-quarters: groups 1..3 -> LDS (aliased, stage is dead) -> grp0
    __syncthreads();
    if (grp != 0) {
        #pragma unroll
        for (int i = 0; i < 4; ++i)
            #pragma unroll
            for (int j = 0; j < 4; ++j)
                sm.Cred[grp - 1][i * 4 + j][tid] = acc[i][j];
    }
    __syncthreads();
    if (grp == 0) {
        #pragma unroll
        for (int g = 0; g < 3; ++g)
            #pragma unroll
            for (int i = 0; i < 4; ++i)
                #pragma unroll
                for (int j = 0; j < 4; ++j)
                    acc[i][j] += sm.Cred[g][i * 4 + j][tid];

        if (iskt) {
            const long gbase = ((long)bz * 32 + ((m0 + tm) >> 3)) * PADK * 8 + (tm & 7);
            #pragma unroll
            for (int j = 0; j < 4; ++j) {
                half4_t h4;
                #pragma unroll
                for (int i = 0; i < 4; ++i) {
                    float e = __builtin_amdgcn_exp2f(acc[i][j] * TWO_LOG2E);
                    h4[i] = (_Float16)fminf(e, 60000.0f);
                }
                *(half4_t*)&Ebuf[gbase + (long)(n0 + tn + j) * 8] = h4;
            }
        } else {
            #pragma unroll
            for (int i = 0; i < 4; ++i) {
                float4 f4v = { __builtin_amdgcn_exp2f(acc[i][0] * TWO_LOG2E),
                               __builtin_amdgcn_exp2f(acc[i][1] * TWO_LOG2E),
                               __builtin_amdgcn_exp2f(acc[i][2] * TWO_LOG2E),
                               __builtin_amdgcn_exp2f(acc[i][3] * TWO_LOG2E) };
                *(float4*)&Fbuf[((long)bz * NQ_ + m0 + tm + i) * H_ + n0 + tn] = f4v;
            }
        }
    }
}

// r25 attn (champion, 32.34 total): QPB=2, fp16 E half8, SGPR F/v, stagger.
__global__ __launch_bounds__(512, 2)
void attn_main(const half8* __restrict__ Eh,   // [B][32][PADK]
               const float* __restrict__ Fbuf, // [B][NQ][H]
               const float* __restrict__ v,    // [H]
               float* __restrict__ out)        // [B][NQ][NK]
{
    const int k = threadIdx.x, b = blockIdx.y, q0 = blockIdx.x * 2;
    const int sb = (blockIdx.x & 7) * 4;       // staggered row-group start

    const half8* kp   = Eh + (long)b * 32 * PADK + k;
    const float4* F0p = (const float4*)(Fbuf + ((long)b * NQ_ + q0) * H_);
    const float4* F1p = F0p + (H_ / 4);
    const float4* v4p = (const float4*)v;

    float T0 = 0.f, T1 = 0.f;

    half8 ka0 = kp[(long)(sb + 0) * PADK], ka1 = kp[(long)(sb + 1) * PADK],
          ka2 = kp[(long)(sb + 2) * PADK], ka3 = kp[(long)(sb + 3) * PADK];
    half8 kn0 = ka0, kn1 = ka1, kn2 = ka2, kn3 = ka3;

#define QTERM(T, E0, E1, E2, E3, FQ, VV)                                      \
    {                                                                         \
        float d0 = fmaf(E0, FQ.x, 1.f), d1 = fmaf(E1, FQ.y, 1.f);             \
        float d2 = fmaf(E2, FQ.z, 1.f), d3 = fmaf(E3, FQ.w, 1.f);             \
        float D01 = d0 * d1, D23 = d2 * d3;                                   \
        float N01 = fmaf(VV.x, d1, VV.y * d0);                                \
        float N23 = fmaf(VV.z, d3, VV.w * d2);                                \
        float N   = fmaf(N01, D23, N23 * D01);                                \
        T = fmaf(N, __builtin_amdgcn_rcpf(D01 * D23), T);                     \
    }
#define PROW(KV, R)                                                           \
    {                                                                         \
        float e0 = (float)KV[0], e1 = (float)KV[1], e2 = (float)KV[2],        \
              e3 = (float)KV[3], e4 = (float)KV[4], e5 = (float)KV[5],        \
              e6 = (float)KV[6], e7 = (float)KV[7];                           \
        float4 va  = v4p[2*(R)],   vb  = v4p[2*(R)+1];                        \
        float4 f0a = F0p[2*(R)],   f0b = F0p[2*(R)+1];                        \
        float4 f1a = F1p[2*(R)],   f1b = F1p[2*(R)+1];                        \
        QTERM(T0, e0, e1, e2, e3, f0a, va)                                    \
        QTERM(T0, e4, e5, e6, e7, f0b, vb)                                    \
        QTERM(T1, e0, e1, e2, e3, f1a, va)                                    \
        QTERM(T1, e4, e5, e6, e7, f1b, vb)                                    \
    }

    for (int gg = 0; gg < 32; gg += 4) {
        const int g = (gg + sb) & 31;          // rotated row-group
        if (gg + 4 < 32) {
            const int gn = (g + 4) & 31;
            kn0 = kp[(long)(gn + 0) * PADK];
            kn1 = kp[(long)(gn + 1) * PADK];
            kn2 = kp[(long)(gn + 2) * PADK];
            kn3 = kp[(long)(gn + 3) * PADK];
        }
        PROW(ka0, g + 0)
        PROW(ka1, g + 1)
        PROW(ka2, g + 2)
        PROW(ka3, g + 3)
        ka0 = kn0; ka1 = kn1; ka2 = kn2; ka3 = kn3;
    }
#undef PROW
#undef QTERM

    float val0 = -2.f * T0;
    float val1 = -2.f * T1;

    // ---- log-softmax over k, no max pass (|val| <= 2*sum|v| ~ 16, safe) ----
    __shared__ float red[8][2];
    const int lane = k & 63, wv = k >> 6;

    float e0 = __builtin_amdgcn_exp2f(val0 * 1.4426950408889634f);
    float e1 = __builtin_amdgcn_exp2f(val1 * 1.4426950408889634f);
    #pragma unroll
    for (int o = 32; o; o >>= 1) {
        e0 += __shfl_xor(e0, o, 64);
        e1 += __shfl_xor(e1, o, 64);
    }
    if (lane == 0) { red[wv][0] = e0; red[wv][1] = e1; }
    __syncthreads();
    float s0 = 0.f, s1 = 0.f;
    #pragma unroll
    for (int w = 0; w < 8; ++w) { s0 += red[w][0]; s1 += red[w][1]; }

    float l0 = __builtin_amdgcn_logf(s0) * 0.6931471805599453f;
    float l1 = __builtin_amdgcn_logf(s1) * 0.6931471805599453f;
    out[((long)b * NQ_ + q0 + 0) * NK_ + k] = val0 - l0;
    out[((long)b * NQ_ + q0 + 1) * NK_ + k] = val1 - l1;
}

extern "C" void kernel_launch(void* const* d_in, const int* in_sizes, int n_in,
                              void* d_out, int out_size, void* d_ws, size_t ws_size,
                              hipStream_t stream)
{
    const float* xq = (const float*)d_in[0];  // (4,256,256)
    const float* xk = (const float*)d_in[1];  // (4,512,256)
    const float* w1 = (const float*)d_in[2];  // (256,256) out,in
    const float* w2 = (const float*)d_in[3];  // (256,256)
    const float* v  = (const float*)d_in[4];  // (1,256)
    float* out = (float*)d_out;

    _Float16* Ebuf = (_Float16*)d_ws;                     // ~1.06MB fp16
    float* Fbuf = (float*)((char*)d_ws + (size_t)B_ * 32 * PADK * 8 * 2);  // 1MB f32

    gemm_fused<<<dim3(192), 1024, 0, stream>>>(xq, xk, w1, w2, Ebuf, Fbuf);
    attn_main<<<dim3(NQ_ / 2, B_), 512, 0, stream>>>(
        (const half8*)Ebuf, Fbuf, v, out);
}

// Round 30
// 31.683 us; speedup vs baseline: 1.1676x; 1.1676x over previous
//
#include <hip/hip_runtime.h>

#define B_  4
#define NQ_ 256
#define NK_ 512
#define H_  256
#define PADK 520   // half8s per E row: stride 8320B, breaks 8KB aliasing

typedef _Float16 half8  __attribute__((ext_vector_type(8)));
typedef _Float16 half4_t __attribute__((ext_vector_type(4)));

// 2*log2(e): exp2(x*TWO_LOG2E) = e^{2x}
#define TWO_LOG2E 2.8853900817779268f

// CHAMPION (r25, 32.34us): SPLIT-K2 gemm -- 192 tiles, 512 threads/block;
// warp-group g = tid>>8 computes K-half [g*128,+128) in its own LDS stage
// buffers -> 2 waves/SIMD so one group's VALU overlaps the other's LDS/VMEM.
// Partials combined via LDS Cred (column-per-thread, conflict-free).
__global__ __launch_bounds__(512)
void gemm_fused(const float* __restrict__ xq, const float* __restrict__ xk,
                const float* __restrict__ w1, const float* __restrict__ w2,
                _Float16* __restrict__ Ebuf,  // [B][32][PADK][8] halves
                float* __restrict__ Fbuf)     // [B][NQ][H]
{
    constexpr int BK = 32;
    const float* A; const float* Bm;
    int m0, n0, bz; bool iskt;
    {
        int id = blockIdx.x;
        if (id < 128) {                      // kt: M=H(o), N=NK(k)
            iskt = true;
            bz = id >> 5; int t = id & 31;
            m0 = (t >> 3) * 64; n0 = (t & 7) * 64;
            A = w1; Bm = xk + (long)bz * NK_ * H_;
        } else {                             // qt: M=NQ(q), N=H(o)
            iskt = false;
            id -= 128;
            bz = id >> 4; int t = id & 15;
            m0 = (t >> 2) * 64; n0 = (t & 3) * 64;
            A = xq + (long)bz * NQ_ * H_; Bm = w2;
        }
    }
    const int lda = H_, ldb = H_;
    const int ks = (blockIdx.x & 7) * BK;    // per-block K stagger (r22 win)

    __shared__ float As[2][BK][68];
    __shared__ float Bs[2][BK][68];
    __shared__ float Cred[16][260];          // grp1 partials; col/thread

    const int tid  = threadIdx.x & 255;
    const int grp  = threadIdx.x >> 8;       // K-half owner
    const int kofs = grp * 128;
    const int lrow = tid >> 2;
    const int lk   = (tid & 3) * 8;
    const int tm   = (tid >> 4) * 4;
    const int tn   = (tid & 15) * 4;

    float acc[4][4] = {};

    int kt0 = (ks + kofs) & (H_ - 1);
    float4 a0_r = *(const float4*)&A [(long)(m0 + lrow) * lda + kt0 + lk];
    float4 a1_r = *(const float4*)&A [(long)(m0 + lrow) * lda + kt0 + lk + 4];
    float4 b0_r = *(const float4*)&Bm[(long)(n0 + lrow) * ldb + kt0 + lk];
    float4 b1_r = *(const float4*)&Bm[(long)(n0 + lrow) * ldb + kt0 + lk + 4];
    float4 a0_n = a0_r, a1_n = a1_r, b0_n = b0_r, b1_n = b1_r;

    for (int t = 0; t < 128; t += BK) {      // 4 iters per group
        __syncthreads();
        As[grp][lk+0][lrow]=a0_r.x; As[grp][lk+1][lrow]=a0_r.y;
        As[grp][lk+2][lrow]=a0_r.z; As[grp][lk+3][lrow]=a0_r.w;
        As[grp][lk+4][lrow]=a1_r.x; As[grp][lk+5][lrow]=a1_r.y;
        As[grp][lk+6][lrow]=a1_r.z; As[grp][lk+7][lrow]=a1_r.w;
        Bs[grp][lk+0][lrow]=b0_r.x; Bs[grp][lk+1][lrow]=b0_r.y;
        Bs[grp][lk+2][lrow]=b0_r.z; Bs[grp][lk+3][lrow]=b0_r.w;
        Bs[grp][lk+4][lrow]=b1_r.x; Bs[grp][lk+5][lrow]=b1_r.y;
        Bs[grp][lk+6][lrow]=b1_r.z; Bs[grp][lk+7][lrow]=b1_r.w;
        if (t + BK < 128) {
            const int ktn = (ks + kofs + t + BK) & (H_ - 1);
            a0_n = *(const float4*)&A [(long)(m0 + lrow) * lda + ktn + lk];
            a1_n = *(const float4*)&A [(long)(m0 + lrow) * lda + ktn + lk + 4];
            b0_n = *(const float4*)&Bm[(long)(n0 + lrow) * ldb + ktn + lk];
            b1_n = *(const float4*)&Bm[(long)(n0 + lrow) * ldb + ktn + lk + 4];
        }
        __syncthreads();
        #pragma unroll
        for (int kk = 0; kk < BK; ++kk) {
            float4 av = *(const float4*)&As[grp][kk][tm];
            float4 bv = *(const float4*)&Bs[grp][kk][tn];
            float am[4] = {av.x, av.y, av.z, av.w};
            float bn[4] = {bv.x, bv.y, bv.z, bv.w};
            #pragma unroll
            for (int i = 0; i < 4; ++i)
                #pragma unroll
                for (int j = 0; j < 4; ++j)
                    acc[i][j] = fmaf(am[i], bn[j], acc[i][j]);
        }
        a0_r = a0_n; a1_r = a1_n; b0_r = b0_n; b1_r = b1_n;
    }

    // combine K-halves: grp1 -> LDS -> grp0
    __syncthreads();
    if (grp == 1) {
        #pragma unroll
        for (int i = 0; i < 4; ++i)
            #pragma unroll
            for (int j = 0; j < 4; ++j)
                Cred[i * 4 + j][tid] = acc[i][j];
    }
    __syncthreads();
    if (grp == 0) {
        #pragma unroll
        for (int i = 0; i < 4; ++i)
            #pragma unroll
            for (int j = 0; j < 4; ++j)
                acc[i][j] += Cred[i * 4 + j][tid];

        if (iskt) {
            const long gbase = ((long)bz * 32 + ((m0 + tm) >> 3)) * PADK * 8 + (tm & 7);
            #pragma unroll
            for (int j = 0; j < 4; ++j) {
                half4_t h4;
                #pragma unroll
                for (int i = 0; i < 4; ++i) {
                    float e = __builtin_amdgcn_exp2f(acc[i][j] * TWO_LOG2E);
                    h4[i] = (_Float16)fminf(e, 60000.0f);
                }
                *(half4_t*)&Ebuf[gbase + (long)(n0 + tn + j) * 8] = h4;
            }
        } else {
            #pragma unroll
            for (int i = 0; i < 4; ++i) {
                float4 f4v = { __builtin_amdgcn_exp2f(acc[i][0] * TWO_LOG2E),
                               __builtin_amdgcn_exp2f(acc[i][1] * TWO_LOG2E),
                               __builtin_amdgcn_exp2f(acc[i][2] * TWO_LOG2E),
                               __builtin_amdgcn_exp2f(acc[i][3] * TWO_LOG2E) };
                *(float4*)&Fbuf[((long)bz * NQ_ + m0 + tm + i) * H_ + n0 + tn] = f4v;
            }
        }
    }
}

// CHAMPION attn (r22/r25): QPB=2, fp16 E half8 (1 load per 8h), SGPR F/v,
// convoy-stagger, 2-group rotating E prefetch.
// prod[q,k] = -2 * sum_h v[h]/(1 + E[h,k]*F[q,h]); Sum v cancels in LSM.
__global__ __launch_bounds__(512, 2)
void attn_main(const half8* __restrict__ Eh,   // [B][32][PADK]
               const float* __restrict__ Fbuf, // [B][NQ][H]
               const float* __restrict__ v,    // [H]
               float* __restrict__ out)        // [B][NQ][NK]
{
    const int k = threadIdx.x, b = blockIdx.y, q0 = blockIdx.x * 2;
    const int sb = (blockIdx.x & 7) * 4;       // staggered row-group start

    const half8* kp   = Eh + (long)b * 32 * PADK + k;
    const float4* F0p = (const float4*)(Fbuf + ((long)b * NQ_ + q0) * H_);
    const float4* F1p = F0p + (H_ / 4);
    const float4* v4p = (const float4*)v;

    float T0 = 0.f, T1 = 0.f;

    half8 ka0 = kp[(long)(sb + 0) * PADK], ka1 = kp[(long)(sb + 1) * PADK],
          ka2 = kp[(long)(sb + 2) * PADK], ka3 = kp[(long)(sb + 3) * PADK];
    half8 kn0 = ka0, kn1 = ka1, kn2 = ka2, kn3 = ka3;

#define QTERM(T, E0, E1, E2, E3, FQ, VV)                                      \
    {                                                                         \
        float d0 = fmaf(E0, FQ.x, 1.f), d1 = fmaf(E1, FQ.y, 1.f);             \
        float d2 = fmaf(E2, FQ.z, 1.f), d3 = fmaf(E3, FQ.w, 1.f);             \
        float D01 = d0 * d1, D23 = d2 * d3;                                   \
        float N01 = fmaf(VV.x, d1, VV.y * d0);                                \
        float N23 = fmaf(VV.z, d3, VV.w * d2);                                \
        float N   = fmaf(N01, D23, N23 * D01);                                \
        T = fmaf(N, __builtin_amdgcn_rcpf(D01 * D23), T);                     \
    }
#define PROW(KV, R)                                                           \
    {                                                                         \
        float e0 = (float)KV[0], e1 = (float)KV[1], e2 = (float)KV[2],        \
              e3 = (float)KV[3], e4 = (float)KV[4], e5 = (float)KV[5],        \
              e6 = (float)KV[6], e7 = (float)KV[7];                           \
        float4 va  = v4p[2*(R)],   vb  = v4p[2*(R)+1];                        \
        float4 f0a = F0p[2*(R)],   f0b = F0p[2*(R)+1];                        \
        float4 f1a = F1p[2*(R)],   f1b = F1p[2*(R)+1];                        \
        QTERM(T0, e0, e1, e2, e3, f0a, va)                                    \
        QTERM(T0, e4, e5, e6, e7, f0b, vb)                                    \
        QTERM(T1, e0, e1, e2, e3, f1a, va)                                    \
        QTERM(T1, e4, e5, e6, e7, f1b, vb)                                    \
    }

    for (int gg = 0; gg < 32; gg += 4) {
        const int g = (gg + sb) & 31;          // rotated row-group
        if (gg + 4 < 32) {
            const int gn = (g + 4) & 31;
            kn0 = kp[(long)(gn + 0) * PADK];
            kn1 = kp[(long)(gn + 1) * PADK];
            kn2 = kp[(long)(gn + 2) * PADK];
            kn3 = kp[(long)(gn + 3) * PADK];
        }
        PROW(ka0, g + 0)
        PROW(ka1, g + 1)
        PROW(ka2, g + 2)
        PROW(ka3, g + 3)
        ka0 = kn0; ka1 = kn1; ka2 = kn2; ka3 = kn3;
    }
#undef PROW
#undef QTERM

    float val0 = -2.f * T0;
    float val1 = -2.f * T1;

    // ---- log-softmax over k, no max pass (|val| <= 2*sum|v| ~ 16, safe) ----
    __shared__ float red[8][2];
    const int lane = k & 63, wv = k >> 6;

    float e0 = __builtin_amdgcn_exp2f(val0 * 1.4426950408889634f);
    float e1 = __builtin_amdgcn_exp2f(val1 * 1.4426950408889634f);
    #pragma unroll
    for (int o = 32; o; o >>= 1) {
        e0 += __shfl_xor(e0, o, 64);
        e1 += __shfl_xor(e1, o, 64);
    }
    if (lane == 0) { red[wv][0] = e0; red[wv][1] = e1; }
    __syncthreads();
    float s0 = 0.f, s1 = 0.f;
    #pragma unroll
    for (int w = 0; w < 8; ++w) { s0 += red[w][0]; s1 += red[w][1]; }

    float l0 = __builtin_amdgcn_logf(s0) * 0.6931471805599453f;
    float l1 = __builtin_amdgcn_logf(s1) * 0.6931471805599453f;
    out[((long)b * NQ_ + q0 + 0) * NK_ + k] = val0 - l0;
    out[((long)b * NQ_ + q0 + 1) * NK_ + k] = val1 - l1;
}

extern "C" void kernel_launch(void* const* d_in, const int* in_sizes, int n_in,
                              void* d_out, int out_size, void* d_ws, size_t ws_size,
                              hipStream_t stream)
{
    const float* xq = (const float*)d_in[0];  // (4,256,256)
    const float* xk = (const float*)d_in[1];  // (4,512,256)
    const float* w1 = (const float*)d_in[2];  // (256,256) out,in
    const float* w2 = (const float*)d_in[3];  // (256,256)
    const float* v  = (const float*)d_in[4];  // (1,256)
    float* out = (float*)d_out;

    _Float16* Ebuf = (_Float16*)d_ws;                     // ~1.06MB fp16
    float* Fbuf = (float*)((char*)d_ws + (size_t)B_ * 32 * PADK * 8 * 2);  // 1MB f32

    gemm_fused<<<dim3(192), 512, 0, stream>>>(xq, xk, w1, w2, Ebuf, Fbuf);
    attn_main<<<dim3(NQ_ / 2, B_), 512, 0, stream>>>(
        (const half8*)Ebuf, Fbuf, v, out);
}